// Round 12
// baseline (1124.761 us; speedup 1.0000x reference)
//
#include <hip/hip_runtime.h>

#define DEV __device__ __forceinline__

// ---------- cross-lane helpers ----------

template <int CTRL>
DEV float dppf(float x) {
  return __int_as_float(__builtin_amdgcn_update_dpp(
      0, __float_as_int(x), CTRL, 0xF, 0xF, true));
}

// Butterfly sum within each 32-lane half; result broadcast to the half.
DEV float wsum32(float v) {
  v += dppf<0xB1>(v);
  v += dppf<0x4E>(v);
  v += dppf<0x141>(v);
  v += dppf<0x140>(v);
#if __has_builtin(__builtin_amdgcn_permlane16_swap)
  {
    auto p = __builtin_amdgcn_permlane16_swap(
        __float_as_uint(v), __float_as_uint(v), false, false);
    v = __uint_as_float(p[0]) + __uint_as_float(p[1]);
  }
#else
  v += __shfl_xor(v, 16, 64);
#endif
  return v;
}

// v[l] + v[l^32]
DEV float halfsum(float v) {
#if __has_builtin(__builtin_amdgcn_permlane32_swap)
  auto p = __builtin_amdgcn_permlane32_swap(
      __float_as_uint(v), __float_as_uint(v), false, false);
  return __uint_as_float(p[0]) + __uint_as_float(p[1]);
#else
  return v + __shfl_xor(v, 32, 64);
#endif
}

#define SLEN 1024
#define NH 8
#define DH 32
#define HSTRIDE 2048  // floats per timestep (B*NH*DH)

// ---------- phase 1: x = softmax32(h), staged into d_out ----------

__global__ __launch_bounds__(256)
void srwm_xsm(const float* __restrict__ h, float* __restrict__ x) {
  int i = blockIdx.x * 256 + threadIdx.x;
  float e = __expf(h[i]);
  x[i] = __fdividef(e, wsum32(e));
}

// ---------- phase 2: the scan. One block (4 waves) per TWO (b,h) chains ----
// Wave w owns one matrix TYPE (0:Wy 1:Wq 2:Wk 3:wb^T) for BOTH chains.
// Lane (r=lane&31, c0) holds cols c0..c0+15 of row r (w<3) or wb^T chunk
// wb[c0+j][r&3] (w==3).
//
// Rationale (R11 post-mortem): the per-step barrier event (skew+sleep+wake+
// drain) is a ~fixed ~500-700cy cost that survived vmcnt surgery, prefetch
// depth, and LDS-read pinning. Amortize it: interleave TWO independent
// chains per block -> one barrier serves two chain-steps, and each chain's
// on-path latency (exp/wsum/fdiv, reductions) hides under the other's issue.
//
// Per-chain math identical to the verified R10 kernel (deferred update):
// entering region T: QV,KV = q_{T-1},k_{T-1}; BW = B_{T-1}[w]; W = W_{T-1};
// preA = W_{T-1} x_T; XS = x_T, XP = x_{T+1}.
//
// Shared layout (byte offsets immediates): slot P in {0,1}, chain C in {0,1}:
//   base = P*576 + C*288 ; q[32]@+0, k[32]@+128, B[4]@+256.

#define DSR128(dst, addr, off) \
  asm volatile("ds_read_b128 %0, %1 offset:%2" : "=&v"(dst) : "v"(addr), "i"(off))
#define DSR32(dst, addr, off) \
  asm volatile("ds_read_b32 %0, %1 offset:%2" : "=&v"(dst) : "v"(addr), "i"(off))

// ---- pre-barrier: on-path compute + nonlinearity + ship (one chain) ----
#define PRE(T, P, C, QV, KV, BW, XS, PREA, W, XB, UOUT)                       \
  {                                                                           \
    float d0=0.f,d1=0.f,d2=0.f,d3=0.f,s0=0.f,s1=0.f,s2=0.f,s3=0.f;            \
    _Pragma("unroll") for (int i = 0; i < 4; ++i) {                           \
      float4 qv = QV[i], kv = KV[i], xv = XS[i];                              \
      d0 = fmaf(W[4*i+0], qv.x - kv.x, d0);                                   \
      d1 = fmaf(W[4*i+1], qv.y - kv.y, d1);                                   \
      d2 = fmaf(W[4*i+2], qv.z - kv.z, d2);                                   \
      d3 = fmaf(W[4*i+3], qv.w - kv.w, d3);                                   \
      s0 = fmaf(kv.x, xv.x, s0);                                              \
      s1 = fmaf(kv.y, xv.y, s1);                                              \
      s2 = fmaf(kv.z, xv.z, s2);                                              \
      s3 = fmaf(kv.w, xv.w, s3);                                              \
    }                                                                         \
    float dsum = halfsum((d0 + d1) + (d2 + d3));                              \
    float sv   = halfsum((s0 + s1) + (s2 + s3));                              \
    UOUT = BW * dsum;                                                         \
    float aA = fmaf(UOUT, sv, PREA);                                          \
    if (w == 0) {                                                             \
      if (lane < DH) XB[(size_t)(T) * HSTRIDE + lane] = aA;  /* y_T */        \
    } else if (w == 1) {                                                      \
      float e = __expf(aA);                                                   \
      shb[(P)*144 + (C)*72 + r] = __fdividef(e, wsum32(e));                   \
    } else if (w == 2) {                                                      \
      float e = __expf(aA);                                                   \
      shb[(P)*144 + (C)*72 + 32 + r] = __fdividef(e, wsum32(e));              \
    } else {                                                                  \
      float sg = __fdividef(1.f, 1.f + __expf(-aA));                          \
      if (lane < 4) shb[(P)*144 + (C)*72 + 64 + lane] = sg;                   \
    }                                                                         \
  }

// ---- pinned async reads of slot P, chain C (waited next region) ----
#define RD(P, C, QN, KN, BN)                                                  \
  {                                                                           \
    DSR128(QN[0], adC, (P)*576 + (C)*288 +   0);                              \
    DSR128(QN[1], adC, (P)*576 + (C)*288 +  16);                              \
    DSR128(QN[2], adC, (P)*576 + (C)*288 +  32);                              \
    DSR128(QN[3], adC, (P)*576 + (C)*288 +  48);                              \
    DSR128(KN[0], adC, (P)*576 + (C)*288 + 128);                              \
    DSR128(KN[1], adC, (P)*576 + (C)*288 + 144);                              \
    DSR128(KN[2], adC, (P)*576 + (C)*288 + 160);                              \
    DSR128(KN[3], adC, (P)*576 + (C)*288 + 176);                              \
    DSR32 (BN,    adB, (P)*576 + (C)*288 + 256);                              \
  }

// ---- post-barrier register work (hidden under the pinned reads) ----
#define POST(T, KV, U, XS, XP, PREA, W, XB)                                   \
  {                                                                           \
    _Pragma("unroll") for (int i = 0; i < 4; ++i) {                           \
      float4 kv = KV[i];                                                      \
      W[4*i+0] = fmaf(U, kv.x, W[4*i+0]);                                     \
      W[4*i+1] = fmaf(U, kv.y, W[4*i+1]);                                     \
      W[4*i+2] = fmaf(U, kv.z, W[4*i+2]);                                     \
      W[4*i+3] = fmaf(U, kv.w, W[4*i+3]);                                     \
    }                                                                         \
    int t2 = (T) + 2; if (t2 > SLEN - 1) t2 = SLEN - 1;                       \
    { const float* xp_ = XB + (size_t)t2 * HSTRIDE + c0;                      \
      _Pragma("unroll") for (int i = 0; i < 4; ++i)                           \
        XS[i] = *(const float4*)(xp_ + 4 * i); }                              \
    float p0=0.f,p1=0.f,p2=0.f,p3=0.f;                                        \
    _Pragma("unroll") for (int i = 0; i < 4; ++i) {                           \
      float4 xv = XP[i];                                                      \
      p0 = fmaf(W[4*i+0], xv.x, p0);                                          \
      p1 = fmaf(W[4*i+1], xv.y, p1);                                          \
      p2 = fmaf(W[4*i+2], xv.z, p2);                                          \
      p3 = fmaf(W[4*i+3], xv.w, p3);                                          \
    }                                                                         \
    PREA = halfsum((p0 + p1) + (p2 + p3));                                    \
  }

#define REGION2(T, P, Q0, K0, B0, QN0, KN0, BN0, XS0, XP0,                    \
                      Q1, K1, B1, QN1, KN1, BN1, XS1, XP1)                    \
  {                                                                           \
    asm volatile("s_waitcnt lgkmcnt(0)");                                     \
    __builtin_amdgcn_sched_barrier(0);                                        \
    float u0_, u1_;                                                           \
    PRE(T, P, 0, Q0, K0, B0, XS0, preA0, W0, xb0, u0_);                       \
    PRE(T, P, 1, Q1, K1, B1, XS1, preA1, W1, xb1, u1_);                       \
    __builtin_amdgcn_sched_barrier(0);                                        \
    asm volatile("s_waitcnt lgkmcnt(0)");                                     \
    __builtin_amdgcn_sched_barrier(0);                                        \
    __builtin_amdgcn_s_barrier();                                             \
    __builtin_amdgcn_sched_barrier(0);                                        \
    RD(P, 0, QN0, KN0, BN0);                                                  \
    RD(P, 1, QN1, KN1, BN1);                                                  \
    __builtin_amdgcn_sched_barrier(0);                                        \
    POST(T, K0, u0_, XS0, XP0, preA0, W0, xb0);                               \
    POST(T, K1, u1_, XS1, XP1, preA1, W1, xb1);                               \
  }

__global__ __launch_bounds__(256, 1)
void srwm_scan(const float* __restrict__ Wy0, const float* __restrict__ Wq0,
               const float* __restrict__ Wk0, const float* __restrict__ wb0,
               float* xy) {
  __shared__ float shb[2 * 144];  // [P][C][72]: q@0, k@32, B@64

  const int w    = threadIdx.x >> 6;  // wave: matrix type 0..3
  const int lane = threadIdx.x & 63;
  const int r    = lane & 31;
  const int c0   = (lane >> 5) * 16;

  const int bh0 = blockIdx.x * 2;      // chains 2b, 2b+1
  const int bh1 = bh0 + 1;
  const int hd0 = bh0 & 7, hd1 = bh1 & 7;

  const uint32_t lbase = (uint32_t)(uintptr_t)&shb[0];
  const uint32_t adC   = lbase + c0 * 4;
  const uint32_t adB   = lbase + w * 4;

  // ---- load this wave's matrix for both chains ----
  float W0[16], W1[16];
  if (w < 3) {
    const float* src = (w == 0) ? Wy0 : (w == 1) ? Wq0 : Wk0;
    const float* p0_ = src + (hd0 * DH + r) * DH + c0;
    const float* p1_ = src + (hd1 * DH + r) * DH + c0;
#pragma unroll
    for (int j = 0; j < 16; j += 4) {
      *(float4*)&W0[j] = *(const float4*)(p0_ + j);
      *(float4*)&W1[j] = *(const float4*)(p1_ + j);
    }
  } else {
    const int kk = r & 3;
#pragma unroll
    for (int j = 0; j < 16; ++j) {
      W0[j] = wb0[(hd0 * DH + c0 + j) * 4 + kk];
      W1[j] = wb0[(hd1 * DH + c0 + j) * 4 + kk];
    }
  }

  float* xb0 = xy + bh0 * DH;
  float* xb1 = xy + bh1 * DH;

  // ---- prologue per chain: X0 <- x_0, X1 <- x_1; preA = W_0 x_0 ----
  float4 XA0[4], XB0[4], XA1[4], XB1[4];
#pragma unroll
  for (int i = 0; i < 4; ++i) {
    XA0[i] = *(const float4*)(xb0 + c0 + 4 * i);
    XB0[i] = *(const float4*)(xb0 + HSTRIDE + c0 + 4 * i);
    XA1[i] = *(const float4*)(xb1 + c0 + 4 * i);
    XB1[i] = *(const float4*)(xb1 + HSTRIDE + c0 + 4 * i);
  }
  float preA0, preA1;
  {
    float p0=0.f,p1=0.f,p2=0.f,p3=0.f, q0=0.f,q1=0.f,q2=0.f,q3=0.f;
#pragma unroll
    for (int i = 0; i < 4; ++i) {
      float4 xv = XA0[i], yv = XA1[i];
      p0 = fmaf(W0[4*i+0], xv.x, p0);
      p1 = fmaf(W0[4*i+1], xv.y, p1);
      p2 = fmaf(W0[4*i+2], xv.z, p2);
      p3 = fmaf(W0[4*i+3], xv.w, p3);
      q0 = fmaf(W1[4*i+0], yv.x, q0);
      q1 = fmaf(W1[4*i+1], yv.y, q1);
      q2 = fmaf(W1[4*i+2], yv.z, q2);
      q3 = fmaf(W1[4*i+3], yv.w, q3);
    }
    preA0 = halfsum((p0 + p1) + (p2 + p3));
    preA1 = halfsum((q0 + q1) + (q2 + q3));
  }

  // q_{-1}=k_{-1}=0 (d=0, u=0), B_{-1}=0
  float4 QA0[4], KA0[4], QB0[4], KB0[4];
  float4 QA1[4], KA1[4], QB1[4], KB1[4];
  const float4 z4 = {0.f, 0.f, 0.f, 0.f};
#pragma unroll
  for (int i = 0; i < 4; ++i) {
    QA0[i] = z4; KA0[i] = z4; QA1[i] = z4; KA1[i] = z4;
  }
  float BwA0 = 0.f, BwB0 = 0.f, BwA1 = 0.f, BwB1 = 0.f;

  __syncthreads();

  for (int t = 0; t < SLEN; t += 2) {
    REGION2(t,     0, QA0, KA0, BwA0, QB0, KB0, BwB0, XA0, XB0,
                      QA1, KA1, BwA1, QB1, KB1, BwB1, XA1, XB1);
    REGION2(t + 1, 1, QB0, KB0, BwB0, QA0, KA0, BwA0, XB0, XA0,
                      QB1, KB1, BwB1, QA1, KA1, BwA1, XB1, XA1);
  }
}

// ---------- phase 3: out = h + ys @ Wout^T  (in-place over ys==out) ----------

__global__ __launch_bounds__(256)
void srwm_proj(const float* __restrict__ h, const float* __restrict__ ys,
               const float* __restrict__ Wout, float* __restrict__ out) {
  __shared__ float ytile[32][256];  // 32 KB
  const int r0  = blockIdx.x * 32;
  const int tid = threadIdx.x;

  const float4* src = (const float4*)(ys + (size_t)r0 * 256);
  float4*       dst = (float4*)(&ytile[0][0]);
#pragma unroll
  for (int i = 0; i < 8; ++i) dst[tid + i * 256] = src[tid + i * 256];
  __syncthreads();

  float acc[32];
#pragma unroll
  for (int m = 0; m < 32; ++m) acc[m] = 0.f;

  const float* wrow = Wout + (size_t)tid * 256;
  for (int k = 0; k < 256; k += 4) {
    float4 wv = *(const float4*)(wrow + k);
#pragma unroll
    for (int m = 0; m < 32; ++m) {
      float4 y4 = *(const float4*)(&ytile[m][k]);
      acc[m] = fmaf(wv.x, y4.x,
               fmaf(wv.y, y4.y,
               fmaf(wv.z, y4.z,
               fmaf(wv.w, y4.w, acc[m]))));
    }
  }

#pragma unroll
  for (int m = 0; m < 32; ++m) {
    int row = r0 + m;
    out[(size_t)row * 256 + tid] = h[(size_t)row * 256 + tid] + acc[m];
  }
}

// ---------- launcher ----------

extern "C" void kernel_launch(void* const* d_in, const int* in_sizes, int n_in,
                              void* d_out, int out_size, void* d_ws, size_t ws_size,
                              hipStream_t stream) {
  const float* h    = (const float*)d_in[0];
  const float* Wy0  = (const float*)d_in[1];
  const float* Wq0  = (const float*)d_in[2];
  const float* Wk0  = (const float*)d_in[3];
  const float* wb0  = (const float*)d_in[4];
  const float* Wout = (const float*)d_in[5];
  float* out = (float*)d_out;

  // d_out triple duty: x (phase1) -> progressively overwritten by y (phase2)
  // -> final output (phase3, in-place via LDS tile).
  srwm_xsm <<<SLEN * HSTRIDE / 256, 256, 0, stream>>>(h, out);
  srwm_scan<<<32, 256, 0, stream>>>(Wy0, Wq0, Wk0, wb0, out);
  srwm_proj<<<256, 256, 0, stream>>>(h, out, Wout, out);
}

// Round 13
// 566.517 us; speedup vs baseline: 1.9854x; 1.9854x over previous
//
#include <hip/hip_runtime.h>

#define DEV __device__ __forceinline__

// ---------- cross-lane helpers ----------

template <int CTRL>
DEV float dppf(float x) {
  return __int_as_float(__builtin_amdgcn_update_dpp(
      0, __float_as_int(x), CTRL, 0xF, 0xF, true));
}

// Butterfly sum within each 32-lane half; result broadcast to the half.
DEV float wsum32(float v) {
  v += dppf<0xB1>(v);
  v += dppf<0x4E>(v);
  v += dppf<0x141>(v);
  v += dppf<0x140>(v);
#if __has_builtin(__builtin_amdgcn_permlane16_swap)
  {
    auto p = __builtin_amdgcn_permlane16_swap(
        __float_as_uint(v), __float_as_uint(v), false, false);
    v = __uint_as_float(p[0]) + __uint_as_float(p[1]);
  }
#else
  v += __shfl_xor(v, 16, 64);
#endif
  return v;
}

// v[l] + v[l^32]
DEV float halfsum(float v) {
#if __has_builtin(__builtin_amdgcn_permlane32_swap)
  auto p = __builtin_amdgcn_permlane32_swap(
      __float_as_uint(v), __float_as_uint(v), false, false);
  return __uint_as_float(p[0]) + __uint_as_float(p[1]);
#else
  return v + __shfl_xor(v, 32, 64);
#endif
}

#define SLEN 1024
#define NH 8
#define DH 32
#define HSTRIDE 2048  // floats per timestep (B*NH*DH)

// ---------- phase 1: x = softmax32(h), staged into d_out ----------

__global__ __launch_bounds__(256)
void srwm_xsm(const float* __restrict__ h, float* __restrict__ x) {
  int i = blockIdx.x * 256 + threadIdx.x;
  float e = __expf(h[i]);
  x[i] = __fdividef(e, wsum32(e));
}

// ---------- phase 2: the scan. One block (TWO waves) per (b,h). ----------
// Wave 0 owns Wy+Wq; wave 1 owns Wk+wb^T. Lane (r=lane&31, c0) holds cols
// c0..c0+15 of row r (wb^T chunk wb[c0+j][r&3] for the wb matrix).
//
// Rationale (R12 post-mortem): 4-wave waves ran at ~5 cyc/instr (lone wave
// per SIMD, thin ILP); R3's fat single wave ran at 2.9. The 2-wave split
// doubles per-wave independent work (2 matrix chains + shared s-dot) to
// restore ILP density, halves barrier participants, and strength-reduces
// addressing (running pointers, clamp-free hot loop).
//
// Region semantics = verified R6 dataflow. Entering region for step T:
// QV,KV = q_{T-1},k_{T-1} col-chunks; BP = (beta_a, beta_b)_{T-1};
// Wa,Wb = W_{T-1}; preAa,preAb = W_{T-1} x_T; XS = x_T, XP = x_{T+1}.
//   PRE : dv=q-k ; da=Wa dv ; db=Wb dv ; s=k.x_T ; ua=BP.x*da ; ub=BP.y*db
//         aA=preAa+ua*s ; aB=preAb+ub*s
//         w0: y_T=aA -> global, q_T=softmax(aB) -> slot P
//         w1: k_T=softmax(aA) -> slot P, B_T=sigmoid(aB) -> slot P
//   BARRIER (LDS-only)
//   POST: read q_T,k_T,B-pair from slot P; Wa+=ua(x)k_{T-1}; Wb+=ub(x)k_{T-1};
//         prefetch x_{T+2} into XS; preA* = W_T x_{T+1}
//
// Shared layout, slot P stride 72 floats: q[32]@0, k[32]@32, B[4]@64.

#define BARRIER()                                        \
  do {                                                   \
    __builtin_amdgcn_sched_barrier(0);                   \
    asm volatile("s_waitcnt lgkmcnt(0)");                \
    __builtin_amdgcn_sched_barrier(0);                   \
    __builtin_amdgcn_s_barrier();                        \
    __builtin_amdgcn_sched_barrier(0);                   \
  } while (0)

#define REGION(P, QV, KV, BP, QN, KN, BPN, XS, XP, XPF, YPTR)                 \
  {                                                                           \
    /* ---- PRE: on-path compute ---- */                                      \
    float da0=0.f,da1=0.f,da2=0.f,da3=0.f;                                    \
    float db0=0.f,db1=0.f,db2=0.f,db3=0.f;                                    \
    float s0=0.f,s1=0.f,s2=0.f,s3=0.f;                                        \
    _Pragma("unroll") for (int i = 0; i < 4; ++i) {                           \
      float4 qv = QV[i], kv = KV[i], xv = XS[i];                              \
      float v0 = qv.x - kv.x, v1 = qv.y - kv.y;                               \
      float v2 = qv.z - kv.z, v3 = qv.w - kv.w;                               \
      da0 = fmaf(Wa[4*i+0], v0, da0);                                         \
      da1 = fmaf(Wa[4*i+1], v1, da1);                                         \
      da2 = fmaf(Wa[4*i+2], v2, da2);                                         \
      da3 = fmaf(Wa[4*i+3], v3, da3);                                         \
      db0 = fmaf(Wb[4*i+0], v0, db0);                                         \
      db1 = fmaf(Wb[4*i+1], v1, db1);                                         \
      db2 = fmaf(Wb[4*i+2], v2, db2);                                         \
      db3 = fmaf(Wb[4*i+3], v3, db3);                                         \
      s0 = fmaf(kv.x, xv.x, s0);                                              \
      s1 = fmaf(kv.y, xv.y, s1);                                              \
      s2 = fmaf(kv.z, xv.z, s2);                                              \
      s3 = fmaf(kv.w, xv.w, s3);                                              \
    }                                                                         \
    float da = halfsum((da0 + da1) + (da2 + da3));                            \
    float db = halfsum((db0 + db1) + (db2 + db3));                            \
    float sv = halfsum((s0 + s1) + (s2 + s3));                                \
    float ua = BP.x * da, ub = BP.y * db;                                     \
    float aA = fmaf(ua, sv, preAa);                                           \
    float aB = fmaf(ub, sv, preAb);                                           \
    if (w == 0) {                                                             \
      if (lane < DH) *(YPTR) = aA;  /* y_T */                                 \
      float e = __expf(aB);                                                   \
      shb[(P)*72 + r] = __fdividef(e, wsum32(e));          /* q_T */          \
    } else {                                                                  \
      float e = __expf(aA);                                                   \
      shb[(P)*72 + 32 + r] = __fdividef(e, wsum32(e));     /* k_T */          \
      float sg = __fdividef(1.f, 1.f + __expf(-aB));                          \
      if (lane < 4) shb[(P)*72 + 64 + lane] = sg;          /* B_T */          \
    }                                                                         \
    BARRIER();                                                                \
    /* ---- POST: reads + register work ---- */                               \
    _Pragma("unroll") for (int i = 0; i < 4; ++i) {                           \
      QN[i] = *(const float4*)&shb[(P)*72 + c0 + 4*i];                        \
      KN[i] = *(const float4*)&shb[(P)*72 + 32 + c0 + 4*i];                   \
    }                                                                         \
    BPN = *(const float2*)&shb[(P)*72 + 64 + 2*w];                            \
    _Pragma("unroll") for (int i = 0; i < 4; ++i) {                           \
      float4 kv = KV[i];                                                      \
      Wa[4*i+0] = fmaf(ua, kv.x, Wa[4*i+0]);                                  \
      Wa[4*i+1] = fmaf(ua, kv.y, Wa[4*i+1]);                                  \
      Wa[4*i+2] = fmaf(ua, kv.z, Wa[4*i+2]);                                  \
      Wa[4*i+3] = fmaf(ua, kv.w, Wa[4*i+3]);                                  \
      Wb[4*i+0] = fmaf(ub, kv.x, Wb[4*i+0]);                                  \
      Wb[4*i+1] = fmaf(ub, kv.y, Wb[4*i+1]);                                  \
      Wb[4*i+2] = fmaf(ub, kv.z, Wb[4*i+2]);                                  \
      Wb[4*i+3] = fmaf(ub, kv.w, Wb[4*i+3]);                                  \
    }                                                                         \
    _Pragma("unroll") for (int i = 0; i < 4; ++i)                             \
      XS[i] = *(const float4*)((XPF) + 4*i);                                  \
    float pa0=0.f,pa1=0.f,pa2=0.f,pa3=0.f;                                    \
    float pb0=0.f,pb1=0.f,pb2=0.f,pb3=0.f;                                    \
    _Pragma("unroll") for (int i = 0; i < 4; ++i) {                           \
      float4 xv = XP[i];                                                      \
      pa0 = fmaf(Wa[4*i+0], xv.x, pa0);                                       \
      pa1 = fmaf(Wa[4*i+1], xv.y, pa1);                                       \
      pa2 = fmaf(Wa[4*i+2], xv.z, pa2);                                       \
      pa3 = fmaf(Wa[4*i+3], xv.w, pa3);                                       \
      pb0 = fmaf(Wb[4*i+0], xv.x, pb0);                                       \
      pb1 = fmaf(Wb[4*i+1], xv.y, pb1);                                       \
      pb2 = fmaf(Wb[4*i+2], xv.z, pb2);                                       \
      pb3 = fmaf(Wb[4*i+3], xv.w, pb3);                                       \
    }                                                                         \
    preAa = halfsum((pa0 + pa1) + (pa2 + pa3));                               \
    preAb = halfsum((pb0 + pb1) + (pb2 + pb3));                               \
  }

__global__ __launch_bounds__(128, 1)
void srwm_scan(const float* __restrict__ Wy0, const float* __restrict__ Wq0,
               const float* __restrict__ Wk0, const float* __restrict__ wb0,
               float* xy) {
  __align__(16) __shared__ float shb[2 * 72];  // slot P: q@0, k@32, B@64

  const int bh   = blockIdx.x;        // 0..63
  const int hd   = bh & 7;
  const int w    = threadIdx.x >> 6;  // wave: 0 (Wy,Wq) or 1 (Wk,wb^T)
  const int lane = threadIdx.x & 63;
  const int r    = lane & 31;
  const int c0   = (lane >> 5) * 16;

  // ---- load this wave's two matrices ----
  float Wa[16], Wb[16];
  if (w == 0) {
    const float* pa = Wy0 + (hd * DH + r) * DH + c0;
    const float* pb = Wq0 + (hd * DH + r) * DH + c0;
#pragma unroll
    for (int j = 0; j < 16; j += 4) {
      *(float4*)&Wa[j] = *(const float4*)(pa + j);
      *(float4*)&Wb[j] = *(const float4*)(pb + j);
    }
  } else {
    const float* pa = Wk0 + (hd * DH + r) * DH + c0;
#pragma unroll
    for (int j = 0; j < 16; j += 4) *(float4*)&Wa[j] = *(const float4*)(pa + j);
    const int kk = r & 3;
#pragma unroll
    for (int j = 0; j < 16; ++j) Wb[j] = wb0[(hd * DH + c0 + j) * 4 + kk];
  }

  float* xb = xy + bh * DH;  // x/y for this (b,h): element [t*HSTRIDE + j]

  // ---- prologue: X0 <- x_0, X1 <- x_1; q_{-1}=k_{-1}=0, B_{-1}=0;
  //      preA = W_0 x_0 (u_{-1}=0) ----
  float4 X0[4], X1[4];
#pragma unroll
  for (int i = 0; i < 4; ++i) {
    X0[i] = *(const float4*)(xb + c0 + 4 * i);
    X1[i] = *(const float4*)(xb + HSTRIDE + c0 + 4 * i);
  }
  float preAa, preAb;
  {
    float pa0=0.f,pa1=0.f,pa2=0.f,pa3=0.f;
    float pb0=0.f,pb1=0.f,pb2=0.f,pb3=0.f;
#pragma unroll
    for (int i = 0; i < 4; ++i) {
      float4 xv = X0[i];
      pa0 = fmaf(Wa[4*i+0], xv.x, pa0);
      pa1 = fmaf(Wa[4*i+1], xv.y, pa1);
      pa2 = fmaf(Wa[4*i+2], xv.z, pa2);
      pa3 = fmaf(Wa[4*i+3], xv.w, pa3);
      pb0 = fmaf(Wb[4*i+0], xv.x, pb0);
      pb1 = fmaf(Wb[4*i+1], xv.y, pb1);
      pb2 = fmaf(Wb[4*i+2], xv.z, pb2);
      pb3 = fmaf(Wb[4*i+3], xv.w, pb3);
    }
    preAa = halfsum((pa0 + pa1) + (pa2 + pa3));
    preAb = halfsum((pb0 + pb1) + (pb2 + pb3));
  }

  float4 QA[4], KA[4], QB[4], KB[4];
  const float4 z4 = {0.f, 0.f, 0.f, 0.f};
#pragma unroll
  for (int i = 0; i < 4; ++i) { QA[i] = z4; KA[i] = z4; }
  float2 BPA = {0.f, 0.f}, BPB = {0.f, 0.f};

  __syncthreads();

  // hot loop: strength-reduced pointers, no clamp (tail peeled)
  const float* xpf = xb + 2 * HSTRIDE + c0;  // x_{t+2} for region t
  float*       yst = xb + lane;              // y_t (w0, lane<32)

  for (int t = 0; t < SLEN - 4; t += 2) {
    REGION(0, QA, KA, BPA, QB, KB, BPB, X0, X1, xpf,           yst);
    REGION(1, QB, KB, BPB, QA, KA, BPA, X1, X0, xpf + HSTRIDE, yst + HSTRIDE);
    xpf += 2 * HSTRIDE;
    yst += 2 * HSTRIDE;
  }
  // tail: t = 1020..1023, prefetch clamped to x_{SLEN-1}
  {
    const float* xlast = xb + (size_t)(SLEN - 1) * HSTRIDE + c0;
    REGION(0, QA, KA, BPA, QB, KB, BPB, X0, X1, xlast - HSTRIDE, yst);
    REGION(1, QB, KB, BPB, QA, KA, BPA, X1, X0, xlast,           yst + HSTRIDE);
    yst += 2 * HSTRIDE;
    REGION(0, QA, KA, BPA, QB, KB, BPB, X0, X1, xlast, yst);
    REGION(1, QB, KB, BPB, QA, KA, BPA, X1, X0, xlast, yst + HSTRIDE);
  }
}

// ---------- phase 3: out = h + ys @ Wout^T  (in-place over ys==out) ----------

__global__ __launch_bounds__(256)
void srwm_proj(const float* __restrict__ h, const float* __restrict__ ys,
               const float* __restrict__ Wout, float* __restrict__ out) {
  __shared__ float ytile[32][256];  // 32 KB
  const int r0  = blockIdx.x * 32;
  const int tid = threadIdx.x;

  const float4* src = (const float4*)(ys + (size_t)r0 * 256);
  float4*       dst = (float4*)(&ytile[0][0]);
#pragma unroll
  for (int i = 0; i < 8; ++i) dst[tid + i * 256] = src[tid + i * 256];
  __syncthreads();

  float acc[32];
#pragma unroll
  for (int m = 0; m < 32; ++m) acc[m] = 0.f;

  const float* wrow = Wout + (size_t)tid * 256;
  for (int k = 0; k < 256; k += 4) {
    float4 wv = *(const float4*)(wrow + k);
#pragma unroll
    for (int m = 0; m < 32; ++m) {
      float4 y4 = *(const float4*)(&ytile[m][k]);
      acc[m] = fmaf(wv.x, y4.x,
               fmaf(wv.y, y4.y,
               fmaf(wv.z, y4.z,
               fmaf(wv.w, y4.w, acc[m]))));
    }
  }

#pragma unroll
  for (int m = 0; m < 32; ++m) {
    int row = r0 + m;
    out[(size_t)row * 256 + tid] = h[(size_t)row * 256 + tid] + acc[m];
  }
}

// ---------- launcher ----------

extern "C" void kernel_launch(void* const* d_in, const int* in_sizes, int n_in,
                              void* d_out, int out_size, void* d_ws, size_t ws_size,
                              hipStream_t stream) {
  const float* h    = (const float*)d_in[0];
  const float* Wy0  = (const float*)d_in[1];
  const float* Wq0  = (const float*)d_in[2];
  const float* Wk0  = (const float*)d_in[3];
  const float* wb0  = (const float*)d_in[4];
  const float* Wout = (const float*)d_in[5];
  float* out = (float*)d_out;

  // d_out triple duty: x (phase1) -> progressively overwritten by y (phase2)
  // -> final output (phase3, in-place via LDS tile).
  srwm_xsm <<<SLEN * HSTRIDE / 256, 256, 0, stream>>>(h, out);
  srwm_scan<<<64, 128, 0, stream>>>(Wy0, Wq0, Wk0, wb0, out);
  srwm_proj<<<256, 256, 0, stream>>>(h, out, Wout, out);
}

// Round 14
// 526.937 us; speedup vs baseline: 2.1345x; 1.0751x over previous
//
#include <hip/hip_runtime.h>

#define DEV __device__ __forceinline__

typedef float f2 __attribute__((ext_vector_type(2)));

// ---------- packed fp32 helpers (VOP3P) ----------

DEV f2 pkfma(f2 a, f2 b, f2 c) {  // c = a*b + c (acc form)
  asm("v_pk_fma_f32 %0, %1, %2, %0" : "+v"(c) : "v"(a), "v"(b));
  return c;
}
DEV f2 pkfma3(f2 a, f2 b, f2 c) {  // d = a*b + c (3-addr form)
  f2 d;
  asm("v_pk_fma_f32 %0, %1, %2, %3" : "=v"(d) : "v"(a), "v"(b), "v"(c));
  return d;
}
DEV f2 pkadd(f2 a, f2 b) {
  f2 d;
  asm("v_pk_add_f32 %0, %1, %2" : "=v"(d) : "v"(a), "v"(b));
  return d;
}

// ---------- cross-lane helpers ----------

template <int CTRL>
DEV float dppf(float x) {
  return __int_as_float(__builtin_amdgcn_update_dpp(
      0, __float_as_int(x), CTRL, 0xF, 0xF, true));
}

// Butterfly sum within each 32-lane half; result broadcast to the half.
DEV float wsum32(float v) {
  v += dppf<0xB1>(v);
  v += dppf<0x4E>(v);
  v += dppf<0x141>(v);
  v += dppf<0x140>(v);
#if __has_builtin(__builtin_amdgcn_permlane16_swap)
  {
    auto p = __builtin_amdgcn_permlane16_swap(
        __float_as_uint(v), __float_as_uint(v), false, false);
    v = __uint_as_float(p[0]) + __uint_as_float(p[1]);
  }
#else
  v += __shfl_xor(v, 16, 64);
#endif
  return v;
}

// v[l] + v[l^32]
DEV float halfsum(float v) {
#if __has_builtin(__builtin_amdgcn_permlane32_swap)
  auto p = __builtin_amdgcn_permlane32_swap(
      __float_as_uint(v), __float_as_uint(v), false, false);
  return __uint_as_float(p[0]) + __uint_as_float(p[1]);
#else
  return v + __shfl_xor(v, 32, 64);
#endif
}

#define SLEN 1024
#define NH 8
#define DH 32
#define HSTRIDE 2048  // floats per timestep (B*NH*DH)

// ---------- phase 1: x = softmax32(h), staged into d_out ----------

__global__ __launch_bounds__(256)
void srwm_xsm(const float* __restrict__ h, float* __restrict__ x) {
  int i = blockIdx.x * 256 + threadIdx.x;
  float e = __expf(h[i]);
  x[i] = __fdividef(e, wsum32(e));
}

// ---------- phase 2: the scan. One block (TWO waves) per (b,h). ----------
// Wave 0 owns Wy+Wq; wave 1 owns Wk+wb^T (as f2 column-pairs). Lane
// (r=lane&31, c0) holds cols c0..c0+15 of row r.
//
// Identical structure/schedule to R13 (2-wave, LDS-only barrier, deferred
// update, strength-reduced pointers, peeled tail). ONE change: all five FMA
// blocks (dv, d-matvec x2, s-dot, W-update x2, preA x2) use v_pk_fma_f32 /
// v_pk_add_f32 — ~112 scalar FMAs -> ~56 packed ops — attacking the measured
// issue-bound regime (R13: 62% per-wave busy, ~725cy issue of 1165cy step).
//
// Shared layout, slot P stride 72 floats: q[32]@0, k[32]@32, B[4]@64.

#define BARRIER()                                        \
  do {                                                   \
    __builtin_amdgcn_sched_barrier(0);                   \
    asm volatile("s_waitcnt lgkmcnt(0)");                \
    __builtin_amdgcn_sched_barrier(0);                   \
    __builtin_amdgcn_s_barrier();                        \
    __builtin_amdgcn_sched_barrier(0);                   \
  } while (0)

// load 16 floats at PTR into f2 DST[8] via 4x float4 (ds/global _b128)
#define LDX4(DST, PTR)                                                        \
  { _Pragma("unroll") for (int i_ = 0; i_ < 4; ++i_) {                        \
      float4 a_ = *(const float4*)((PTR) + 4 * i_);                           \
      DST[2*i_]   = f2{a_.x, a_.y};                                           \
      DST[2*i_+1] = f2{a_.z, a_.w}; } }

#define REGION(P, QV, KV, BP, QN, KN, BPN, XS, XP, XPF, YPTR)                 \
  {                                                                           \
    /* ---- PRE: on-path compute ---- */                                      \
    f2 dv[8];                                                                 \
    _Pragma("unroll") for (int j = 0; j < 8; ++j)                             \
      dv[j] = pkfma3(KV[j], mone, QV[j]);       /* q - k */                   \
    f2 daA={0.f,0.f}, daB={0.f,0.f}, dbA={0.f,0.f}, dbB={0.f,0.f};            \
    f2 sA={0.f,0.f}, sB={0.f,0.f};                                            \
    _Pragma("unroll") for (int j = 0; j < 8; j += 2) {                        \
      daA = pkfma(Wa2[j],   dv[j],   daA);                                    \
      daB = pkfma(Wa2[j+1], dv[j+1], daB);                                    \
      dbA = pkfma(Wb2[j],   dv[j],   dbA);                                    \
      dbB = pkfma(Wb2[j+1], dv[j+1], dbB);                                    \
      sA  = pkfma(KV[j],    XS[j],   sA);                                     \
      sB  = pkfma(KV[j+1],  XS[j+1], sB);                                     \
    }                                                                         \
    f2 dac = pkadd(daA, daB), dbc = pkadd(dbA, dbB), sc = pkadd(sA, sB);      \
    float da = halfsum(dac.x + dac.y);                                        \
    float db = halfsum(dbc.x + dbc.y);                                        \
    float sv = halfsum(sc.x + sc.y);                                          \
    float ua = BP.x * da, ub = BP.y * db;                                     \
    float aA = fmaf(ua, sv, preAa);                                           \
    float aB = fmaf(ub, sv, preAb);                                           \
    if (w == 0) {                                                             \
      if (lane < DH) *(YPTR) = aA;  /* y_T */                                 \
      float e = __expf(aB);                                                   \
      shb[(P)*72 + r] = __fdividef(e, wsum32(e));          /* q_T */          \
    } else {                                                                  \
      float e = __expf(aA);                                                   \
      shb[(P)*72 + 32 + r] = __fdividef(e, wsum32(e));     /* k_T */          \
      float sg = __fdividef(1.f, 1.f + __expf(-aB));                          \
      if (lane < 4) shb[(P)*72 + 64 + lane] = sg;          /* B_T */          \
    }                                                                         \
    BARRIER();                                                                \
    /* ---- POST: reads + register work ---- */                               \
    LDX4(QN, &shb[(P)*72 + c0]);                                              \
    LDX4(KN, &shb[(P)*72 + 32 + c0]);                                         \
    BPN = *(const float2*)&shb[(P)*72 + 64 + 2*w];                            \
    f2 uua = f2{ua, ua}, uub = f2{ub, ub};                                    \
    _Pragma("unroll") for (int j = 0; j < 8; ++j) {                           \
      Wa2[j] = pkfma(uua, KV[j], Wa2[j]);                                     \
      Wb2[j] = pkfma(uub, KV[j], Wb2[j]);                                     \
    }                                                                         \
    LDX4(XS, XPF);                                /* prefetch x_{T+2} */      \
    f2 paA={0.f,0.f}, paB={0.f,0.f}, pbA={0.f,0.f}, pbB={0.f,0.f};            \
    _Pragma("unroll") for (int j = 0; j < 8; j += 2) {                        \
      paA = pkfma(Wa2[j],   XP[j],   paA);                                    \
      paB = pkfma(Wa2[j+1], XP[j+1], paB);                                    \
      pbA = pkfma(Wb2[j],   XP[j],   pbA);                                    \
      pbB = pkfma(Wb2[j+1], XP[j+1], pbB);                                    \
    }                                                                         \
    f2 pac = pkadd(paA, paB), pbc = pkadd(pbA, pbB);                          \
    preAa = halfsum(pac.x + pac.y);                                           \
    preAb = halfsum(pbc.x + pbc.y);                                           \
  }

__global__ __launch_bounds__(128, 1)
void srwm_scan(const float* __restrict__ Wy0, const float* __restrict__ Wq0,
               const float* __restrict__ Wk0, const float* __restrict__ wb0,
               float* xy) {
  __align__(16) __shared__ float shb[2 * 72];  // slot P: q@0, k@32, B@64

  const int bh   = blockIdx.x;        // 0..63
  const int hd   = bh & 7;
  const int w    = threadIdx.x >> 6;  // wave: 0 (Wy,Wq) or 1 (Wk,wb^T)
  const int lane = threadIdx.x & 63;
  const int r    = lane & 31;
  const int c0   = (lane >> 5) * 16;

  const f2 mone = f2{-1.f, -1.f};

  // ---- load this wave's two matrices as f2 column-pairs ----
  f2 Wa2[8], Wb2[8];
  if (w == 0) {
    const float* pa = Wy0 + (hd * DH + r) * DH + c0;
    const float* pb = Wq0 + (hd * DH + r) * DH + c0;
    LDX4(Wa2, pa);
    LDX4(Wb2, pb);
  } else {
    const float* pa = Wk0 + (hd * DH + r) * DH + c0;
    LDX4(Wa2, pa);
    const int kk = r & 3;
#pragma unroll
    for (int j = 0; j < 8; ++j)
      Wb2[j] = f2{wb0[(hd * DH + c0 + 2*j) * 4 + kk],
                  wb0[(hd * DH + c0 + 2*j + 1) * 4 + kk]};
  }

  float* xb = xy + bh * DH;  // x/y for this (b,h): element [t*HSTRIDE + j]

  // ---- prologue: X0 <- x_0, X1 <- x_1; q_{-1}=k_{-1}=0, B_{-1}=0;
  //      preA = W_0 x_0 (u_{-1}=0) ----
  f2 X0[8], X1[8];
  LDX4(X0, xb + c0);
  LDX4(X1, xb + HSTRIDE + c0);

  float preAa, preAb;
  {
    f2 paA={0.f,0.f}, paB={0.f,0.f}, pbA={0.f,0.f}, pbB={0.f,0.f};
#pragma unroll
    for (int j = 0; j < 8; j += 2) {
      paA = pkfma(Wa2[j],   X0[j],   paA);
      paB = pkfma(Wa2[j+1], X0[j+1], paB);
      pbA = pkfma(Wb2[j],   X0[j],   pbA);
      pbB = pkfma(Wb2[j+1], X0[j+1], pbB);
    }
    f2 pac = pkadd(paA, paB), pbc = pkadd(pbA, pbB);
    preAa = halfsum(pac.x + pac.y);
    preAb = halfsum(pbc.x + pbc.y);
  }

  f2 QA[8], KA[8], QB[8], KB[8];
  const f2 z2 = f2{0.f, 0.f};
#pragma unroll
  for (int j = 0; j < 8; ++j) { QA[j] = z2; KA[j] = z2; }
  float2 BPA = {0.f, 0.f}, BPB = {0.f, 0.f};

  __syncthreads();

  // hot loop: strength-reduced pointers, no clamp (tail peeled)
  const float* xpf = xb + 2 * HSTRIDE + c0;  // x_{t+2} for region t
  float*       yst = xb + lane;              // y_t (w0, lane<32)

  for (int t = 0; t < SLEN - 4; t += 2) {
    REGION(0, QA, KA, BPA, QB, KB, BPB, X0, X1, xpf,           yst);
    REGION(1, QB, KB, BPB, QA, KA, BPA, X1, X0, xpf + HSTRIDE, yst + HSTRIDE);
    xpf += 2 * HSTRIDE;
    yst += 2 * HSTRIDE;
  }
  // tail: t = 1020..1023, prefetch clamped to x_{SLEN-1}
  {
    const float* xlast = xb + (size_t)(SLEN - 1) * HSTRIDE + c0;
    REGION(0, QA, KA, BPA, QB, KB, BPB, X0, X1, xlast - HSTRIDE, yst);
    REGION(1, QB, KB, BPB, QA, KA, BPA, X1, X0, xlast,           yst + HSTRIDE);
    yst += 2 * HSTRIDE;
    REGION(0, QA, KA, BPA, QB, KB, BPB, X0, X1, xlast, yst);
    REGION(1, QB, KB, BPB, QA, KA, BPA, X1, X0, xlast, yst + HSTRIDE);
  }
}

// ---------- phase 3: out = h + ys @ Wout^T  (in-place over ys==out) ----------

__global__ __launch_bounds__(256)
void srwm_proj(const float* __restrict__ h, const float* __restrict__ ys,
               const float* __restrict__ Wout, float* __restrict__ out) {
  __shared__ float ytile[32][256];  // 32 KB
  const int r0  = blockIdx.x * 32;
  const int tid = threadIdx.x;

  const float4* src = (const float4*)(ys + (size_t)r0 * 256);
  float4*       dst = (float4*)(&ytile[0][0]);
#pragma unroll
  for (int i = 0; i < 8; ++i) dst[tid + i * 256] = src[tid + i * 256];
  __syncthreads();

  float acc[32];
#pragma unroll
  for (int m = 0; m < 32; ++m) acc[m] = 0.f;

  const float* wrow = Wout + (size_t)tid * 256;
  for (int k = 0; k < 256; k += 4) {
    float4 wv = *(const float4*)(wrow + k);
#pragma unroll
    for (int m = 0; m < 32; ++m) {
      float4 y4 = *(const float4*)(&ytile[m][k]);
      acc[m] = fmaf(wv.x, y4.x,
               fmaf(wv.y, y4.y,
               fmaf(wv.z, y4.z,
               fmaf(wv.w, y4.w, acc[m]))));
    }
  }

#pragma unroll
  for (int m = 0; m < 32; ++m) {
    int row = r0 + m;
    out[(size_t)row * 256 + tid] = h[(size_t)row * 256 + tid] + acc[m];
  }
}

// ---------- launcher ----------

extern "C" void kernel_launch(void* const* d_in, const int* in_sizes, int n_in,
                              void* d_out, int out_size, void* d_ws, size_t ws_size,
                              hipStream_t stream) {
  const float* h    = (const float*)d_in[0];
  const float* Wy0  = (const float*)d_in[1];
  const float* Wq0  = (const float*)d_in[2];
  const float* Wk0  = (const float*)d_in[3];
  const float* wb0  = (const float*)d_in[4];
  const float* Wout = (const float*)d_in[5];
  float* out = (float*)d_out;

  // d_out triple duty: x (phase1) -> progressively overwritten by y (phase2)
  // -> final output (phase3, in-place via LDS tile).
  srwm_xsm <<<SLEN * HSTRIDE / 256, 256, 0, stream>>>(h, out);
  srwm_scan<<<64, 128, 0, stream>>>(Wy0, Wq0, Wk0, wb0, out);
  srwm_proj<<<256, 256, 0, stream>>>(h, out, Wout, out);
}